// Round 18
// baseline (214.425 us; speedup 1.0000x reference)
//
#include <hip/hip_runtime.h>
#include <hip/hip_bf16.h>

typedef __hip_bfloat16 bf16;
typedef __attribute__((ext_vector_type(4))) float f32x4;
typedef __attribute__((ext_vector_type(8))) short bf16x8;  // 8 bf16 in 4 VGPRs
typedef __attribute__((ext_vector_type(4))) short bf16x4;  // 4 bf16 in 2 VGPRs

// ---------------------------------------------------------------------------
// helpers
// ---------------------------------------------------------------------------
__device__ __forceinline__ void gload_lds16(const bf16* g, bf16* l) {
  __builtin_amdgcn_global_load_lds(
      (const __attribute__((address_space(1))) unsigned int*)(const void*)g,
      (__attribute__((address_space(3))) unsigned int*)(void*)l,
      16, 0, 0);
}
__device__ __forceinline__ void gload_lds16f(const float* g, float* l) {
  __builtin_amdgcn_global_load_lds(
      (const __attribute__((address_space(1))) unsigned int*)(const void*)g,
      (__attribute__((address_space(3))) unsigned int*)(void*)l,
      16, 0, 0);
}

// XCD-contiguous bijective swizzle; REQUIRES nwg % 8 == 0.
__device__ __forceinline__ int xcd_swz(int orig, int nwg) {
  return (orig & 7) * (nwg >> 3) + (orig >> 3);
}

__device__ __forceinline__ float b2f(ushort u) {
  return __uint_as_float(((unsigned)u) << 16);
}

// 16x16x16 bf16 MFMA (K=16): A-frag = lane{row=l&15, k=(l>>4)*4+0..3}
#if defined(__has_builtin)
#if __has_builtin(__builtin_amdgcn_mfma_f32_16x16x16bf16_1k)
#define HAVE_MFMA16_BUILTIN 1
#endif
#endif
__device__ __forceinline__ f32x4 mfma16(bf16x4 a, bf16x4 b, f32x4 c) {
#ifdef HAVE_MFMA16_BUILTIN
  return __builtin_amdgcn_mfma_f32_16x16x16bf16_1k(a, b, c, 0, 0, 0);
#else
  asm("v_mfma_f32_16x16x16_bf16 %0, %1, %2, %0" : "+v"(c) : "v"(a), "v"(b));
  return c;
#endif
}

// ---------------------------------------------------------------------------
// prep: weights->bf16 (blocks [0,576)), addend table ([576,9984)).
// x is consumed as f32 directly by the QKV GEMM (no conversion pass).
// ---------------------------------------------------------------------------
__global__ void prep_kernel(
    const float* __restrict__ wq, bf16* __restrict__ wqb,
    const float* __restrict__ wp, bf16* __restrict__ wpb,
    const float* __restrict__ mask, const int* __restrict__ pos,
    const float* __restrict__ table, bf16* __restrict__ addend) {
  const int bid = blockIdx.x;
  if (bid < 576) {                         // w_qkv (442368) + w_proj (147456)
    int t = bid * 256 + threadIdx.x;
    const float* src;
    bf16* dst;
    size_t i;
    if (t < 110592) {
      src = wq; dst = wqb; i = (size_t)t * 4;
    } else {
      src = wp; dst = wpb; i = (size_t)(t - 110592) * 4;
    }
    float4 v = *reinterpret_cast<const float4*>(src + i);
    bf16 o[4] = {__float2bfloat16(v.x), __float2bfloat16(v.y),
                 __float2bfloat16(v.z), __float2bfloat16(v.w)};
    *reinterpret_cast<ushort4*>(dst + i) = *reinterpret_cast<const ushort4*>(o);
  } else {                                 // addend: 2,408,448 elems
    int idx = (bid - 576) * 256 + threadIdx.x;
    int c   = idx & 63;
    int rh  = idx >> 6;
    int row = rh % 49;
    int h   = (rh / 49) % 12;
    int w   = rh / (49 * 12);
    int k   = ((c >> 2) & 3) * 16 + (c >> 4) * 4 + (c & 3);
    float v = -1e30f;
    if (k < 49) {
      float m = mask[(w * 49 + row) * 49 + k];
      if (m != 0.0f) {
        v = m;
      } else {
        bool is64 = (pos[1] == 0) & (pos[3] == 0) & (pos[5] == 0) & (pos[7] == 0) &
                    (pos[9] == 0) & (pos[11] == 0) & (pos[13] == 0) & (pos[15] == 0);
        int pi = (w * 49 + row) * 49 + k;
        int p = is64 ? pos[2 * pi] : pos[pi];
        v = table[p * 12 + h];
      }
    }
    addend[idx] = __float2bfloat16(v);
  }
}

// ---------------------------------------------------------------------------
// QKV GEMM with f32 A consumed directly (kills the x->bf16 prep pass):
// R15 pinned structure (128x128, BK=32, 4 waves, 3-slot ring, counted vmcnt).
// A staged f32 via global_load_lds; cvt f32->bf16 in the fragment-read path.
//
// R17 FAILED because the A-staging gave each thread 64B of LDS (lane stride
// 64B) — global_load_lds writes at wave-uniform base + lane*16 (m104 rule),
// scrambling the tile. FIX: each of the 4 A-loads fills a contiguous 4KB LDS
// quarter (rows 32j..32j+31) so per-lane stride is exactly 16B:
//   load j, thread t: row = 32j + (t>>3), chunk pos = t&7,
//   global chunk = (t&7) ^ ((t>>3)&7)   [key = row&7; 32j = 0 mod 8]
//   LDS float offset = j*1024 + t*4  ==  row*32 + pos*4.
// Reader (unchanged): key lr&7, position p = g ^ key -> banks uniform
// (8 accesses/bank, balanced). 6 loads/thread/tile -> vmcnt(6).
// ---------------------------------------------------------------------------
__global__ __launch_bounds__(256) void gemm_qkv(
    const float* __restrict__ A, const bf16* __restrict__ Bm,
    const float* __restrict__ bias, bf16* __restrict__ Cout,
    int M, int N, int K, int nbn, int nwg) {
  __shared__ float Asf[3 * 128 * 32];   // 48 KB (3 x 16 KB)
  __shared__ bf16  Bs[3 * 128 * 32];    // 24 KB (3 x 8 KB)
  const int t = threadIdx.x;
  const int lane = t & 63;
  const int w = t >> 6, wr = w >> 1, wc = w & 1;
  const int lid = xcd_swz(blockIdx.x, nwg);
  const int bm = lid / nbn, bn = lid % nbn;
  const int lr = lane & 15, lg = lane >> 4;

  // A staging (f32): load j covers rows 32j..32j+31 (contiguous LDS quarter,
  // lane stride 16B). Thread t: row 32j+(t>>3), global chunk (t&7)^((t>>3)&7).
  const int akey = (t >> 3) & 7;
  const int agc  = (t & 7) ^ akey;
  const float* ag = A + ((size_t)(bm * 128 + (t >> 3))) * K + agc * 4;
  const int aoff = t * 4;   // floats (16B per thread per load)
  // B staging (bf16): R15 recipe (key (row>>1)&3)
  const int sc = (t & 3) ^ ((t >> 3) & 3);
  const bf16* bg = Bm + ((size_t)(bn * 128 + (t >> 2))) * K + sc * 8;
  const size_t rstepB = (size_t)64 * K;
  const int boff = t * 8;

  auto stage = [&](int tt) {
    const int si = tt % 3;
#pragma unroll
    for (int j = 0; j < 4; j++)
      gload_lds16f(ag + (size_t)j * 32 * K + tt * 32,
                   Asf + si * 4096 + j * 1024 + aoff);
    bf16* bd = Bs + si * 4096 + boff;
    gload_lds16(bg + tt * 32, bd);
    gload_lds16(bg + tt * 32 + rstepB, bd + 2048);
  };

  f32x4 acc[4][4] = {};
  const int nt = K >> 5;   // 12 tiles

  stage(0);
  stage(1);

  const int lgs = lg ^ ((lr >> 1) & 3);   // B reader key
  const int fkey = lr & 7;                // A reader key (= row&7)
  const int cA0 = ((2 * lg) ^ fkey) * 4;       // lo 4 floats (cols lg*8..+4)
  const int cA1 = ((2 * lg + 1) ^ fkey) * 4;   // hi 4 floats

  for (int kt = 0; kt < nt; ++kt) {
    if (kt + 1 < nt)
      asm volatile("s_waitcnt vmcnt(6)" ::: "memory");
    else
      asm volatile("s_waitcnt vmcnt(0)" ::: "memory");
    __builtin_amdgcn_s_barrier();
    if (kt + 2 < nt) stage(kt + 2);

    const int si = kt % 3;
    const float* abase = Asf + si * 4096 + (size_t)(wr * 64 + lr) * 32;
    const bf16* bb = Bs + si * 4096 + (wc * 64 + lr) * 32 + lgs * 8;
    bf16x8 af[4], bff[4];
#pragma unroll
    for (int i = 0; i < 4; i++) {
      const float* rp = abase + (size_t)i * 16 * 32;
      float4 lo = *reinterpret_cast<const float4*>(rp + cA0);
      float4 hi = *reinterpret_cast<const float4*>(rp + cA1);
      bf16 tmp[8] = {__float2bfloat16(lo.x), __float2bfloat16(lo.y),
                     __float2bfloat16(lo.z), __float2bfloat16(lo.w),
                     __float2bfloat16(hi.x), __float2bfloat16(hi.y),
                     __float2bfloat16(hi.z), __float2bfloat16(hi.w)};
      af[i] = *reinterpret_cast<const bf16x8*>(tmp);
    }
#pragma unroll
    for (int j = 0; j < 4; j++) bff[j] = *reinterpret_cast<const bf16x8*>(bb + j * 16 * 32);
#pragma unroll
    for (int i = 0; i < 4; i++)
#pragma unroll
      for (int j = 0; j < 4; j++)
        acc[i][j] = __builtin_amdgcn_mfma_f32_16x16x32_bf16(af[i], bff[j], acc[i][j], 0, 0, 0);
  }

#pragma unroll
  for (int i = 0; i < 4; i++) {
    int row0 = bm * 128 + wr * 64 + i * 16 + lg * 4;
#pragma unroll
    for (int j = 0; j < 4; j++) {
      int col = bn * 128 + wc * 64 + j * 16 + lr;
      float bv = bias[col];
#pragma unroll
      for (int r = 0; r < 4; r++) {
        float v = acc[i][j][r] + bv;
        Cout[(size_t)(row0 + r) * N + col] = __float2bfloat16(v);
      }
    }
  }
}

// ---------------------------------------------------------------------------
// proj GEMM: R10/R15 pinned template (128x128, BK=32, 3-buffer counted vmcnt,
// conflict-free XOR swizzle). C f32 out.
// ---------------------------------------------------------------------------
__global__ __launch_bounds__(256) void gemm_bt(
    const bf16* __restrict__ A, const bf16* __restrict__ Bm,
    const float* __restrict__ bias, float* __restrict__ Cout,
    int M, int N, int K, int nbn, int nwg) {
  __shared__ bf16 As[3 * 128 * 32];
  __shared__ bf16 Bs[3 * 128 * 32];
  const int t = threadIdx.x;
  const int lane = t & 63;
  const int w = t >> 6, wr = w >> 1, wc = w & 1;
  const int lid = xcd_swz(blockIdx.x, nwg);
  const int bm = lid / nbn, bn = lid % nbn;
  const int lr = lane & 15, lg = lane >> 4;

  const int sc = (t & 3) ^ ((t >> 3) & 3);
  const bf16* ag = A + ((size_t)(bm * 128 + (t >> 2))) * K + sc * 8;
  const bf16* bg = Bm + ((size_t)(bn * 128 + (t >> 2))) * K + sc * 8;
  const size_t rstep = (size_t)64 * K;
  const int loff = t * 8;

  auto stage = [&](int tt) {
    const int bi = tt % 3;
    bf16* ad = As + bi * 4096 + loff;
    bf16* bd = Bs + bi * 4096 + loff;
    const bf16* as_ = ag + tt * 32;
    const bf16* bs_ = bg + tt * 32;
    gload_lds16(as_, ad);
    gload_lds16(as_ + rstep, ad + 2048);
    gload_lds16(bs_, bd);
    gload_lds16(bs_ + rstep, bd + 2048);
  };

  f32x4 acc[4][4] = {};
  const int nt = K >> 5;

  stage(0);
  stage(1);

  const int lgs = lg ^ ((lr >> 1) & 3);

  for (int kt = 0; kt < nt; ++kt) {
    if (kt + 1 < nt)
      asm volatile("s_waitcnt vmcnt(4)" ::: "memory");
    else
      asm volatile("s_waitcnt vmcnt(0)" ::: "memory");
    __builtin_amdgcn_s_barrier();
    if (kt + 2 < nt) stage(kt + 2);

    const int bi = kt % 3;
    bf16x8 af[4], bff[4];
    const bf16* ab = As + bi * 4096 + (wr * 64 + lr) * 32 + lgs * 8;
    const bf16* bb = Bs + bi * 4096 + (wc * 64 + lr) * 32 + lgs * 8;
#pragma unroll
    for (int i = 0; i < 4; i++) af[i] = *reinterpret_cast<const bf16x8*>(ab + i * 16 * 32);
#pragma unroll
    for (int j = 0; j < 4; j++) bff[j] = *reinterpret_cast<const bf16x8*>(bb + j * 16 * 32);
#pragma unroll
    for (int i = 0; i < 4; i++)
#pragma unroll
      for (int j = 0; j < 4; j++)
        acc[i][j] = __builtin_amdgcn_mfma_f32_16x16x32_bf16(af[i], bff[j], acc[i][j], 0, 0, 0);
  }

#pragma unroll
  for (int i = 0; i < 4; i++) {
    int row0 = bm * 128 + wr * 64 + i * 16 + lg * 4;
#pragma unroll
    for (int j = 0; j < 4; j++) {
      int col = bn * 128 + wc * 64 + j * 16 + lr;
      float bv = bias[col];
#pragma unroll
      for (int r = 0; r < 4; r++)
        Cout[(size_t)(row0 + r) * N + col] = acc[i][j][r] + bv;
    }
  }
}

// ---------------------------------------------------------------------------
// fused window attention: TWO heads per wave (ILP), 4 waves per block.
// R15 structure, frozen (near its memory-path floor).
// ---------------------------------------------------------------------------
__global__ __launch_bounds__(256) void attn_kernel(
    const bf16* __restrict__ qkv, const bf16* __restrict__ addend,
    bf16* __restrict__ attn_out) {
  const int bid = xcd_swz(blockIdx.x, 1536);
  const int wv = threadIdx.x >> 6;
  const int p = bid * 4 + wv;
  const int b = p / 6;
  const int h0 = (p % 6) * 2;          // handles h0, h0+1
  const int w = b & 63;
  const int lane = threadIdx.x & 63;
  const int lr = lane & 15, lg = lane >> 4;
  const float scale = 0.17677669529663687f;  // 32^-0.5

  __shared__ ushort vT_all[4][2][32][72];   // [wave][head][d][k], 36.9 KB

  const size_t base = (size_t)b * 49 * 1152;

  // --- issue BOTH heads' Q/K loads up front (rows >= 49 clamped to 48)
  bf16x8 qf[2][4], kf[2][4];
#pragma unroll
  for (int hh = 0; hh < 2; hh++) {
    const int h = h0 + hh;
#pragma unroll
    for (int i = 0; i < 4; i++) {
      int rw = i * 16 + lr;
      int row = rw < 49 ? rw : 48;
      qf[hh][i] = *reinterpret_cast<const bf16x8*>(
          qkv + base + (size_t)row * 1152 + h * 32 + lg * 8);
      kf[hh][i] = *reinterpret_cast<const bf16x8*>(
          qkv + base + (size_t)row * 1152 + 384 + h * 32 + lg * 8);
    }
  }

  // --- stage BOTH heads' V transposed: vT[d][k] = V[k][d]
#pragma unroll
  for (int hh = 0; hh < 2; hh++) {
    ushort(*vT)[72] = vT_all[wv][hh];
    const int h = h0 + hh;
    if (lane < 49) {
#pragma unroll
      for (int c4 = 0; c4 < 4; c4++) {
        bf16x8 vv = *reinterpret_cast<const bf16x8*>(
            qkv + base + (size_t)lane * 1152 + 768 + h * 32 + c4 * 8);
#pragma unroll
        for (int cc = 0; cc < 8; cc++) vT[c4 * 8 + cc][lane] = (ushort)vv[cc];
      }
    } else {
#pragma unroll
      for (int c = 0; c < 32; c++) vT[c][lane] = 0;
    }
  }

  // --- per head (serial to cap VGPR): QK^T, no-max softmax, PV, store
#pragma unroll
  for (int hh = 0; hh < 2; hh++) {
    const int h = h0 + hh;
    ushort(*vT)[72] = vT_all[wv][hh];
    const bf16* add_base = addend + (size_t)(w * 12 + h) * 49 * 64;
    bf16x4 pa[4][4];   // [qj][ki]
#pragma unroll
    for (int qj = 0; qj < 4; qj++) {
      f32x4 s[4] = {};
      __builtin_amdgcn_s_setprio(1);
#pragma unroll
      for (int ki = 0; ki < 4; ki++)
        s[ki] = __builtin_amdgcn_mfma_f32_16x16x32_bf16(kf[hh][ki], qf[hh][qj], s[ki], 0, 0, 0);
      __builtin_amdgcn_s_setprio(0);

      int q = qj * 16 + lr;
      int qc = q < 49 ? q : 48;
      const ushort* ap_ = (const ushort*)(add_base + (size_t)qc * 64 + lg * 16);
      bf16x8 a0 = *reinterpret_cast<const bf16x8*>(ap_);      // ki 0,1
      bf16x8 a1 = *reinterpret_cast<const bf16x8*>(ap_ + 8);  // ki 2,3
      float v[12];
      float sum = 0.f;
#pragma unroll
      for (int u = 0; u < 8; u++) {   // ki 0,1
        v[u] = __expf(s[u >> 2][u & 3] * scale + b2f((ushort)a0[u]));
        sum += v[u];
      }
#pragma unroll
      for (int u = 0; u < 4; u++) {   // ki 2
        v[8 + u] = __expf(s[2][u] * scale + b2f((ushort)a1[u]));
        sum += v[8 + u];
      }
      // ki 3: only k=48 is real (lg==0, r==0); its addend is a1[4]
      float e48 = (lg == 0) ? __expf(s[3][0] * scale + b2f((ushort)a1[4])) : 0.0f;
      sum += e48;
      sum += __shfl_xor(sum, 16, 64);
      sum += __shfl_xor(sum, 32, 64);
      float rs = 1.0f / sum;
#pragma unroll
      for (int ki = 0; ki < 3; ki++) {
        bf16x4 pk;
#pragma unroll
        for (int r = 0; r < 4; r++)
          pk[r] = (short)__bfloat16_as_ushort(__float2bfloat16(v[ki * 4 + r] * rs));
        pa[qj][ki] = pk;
      }
      bf16x4 p3;
      p3[0] = (short)__bfloat16_as_ushort(__float2bfloat16(e48 * rs));
      p3[1] = 0; p3[2] = 0; p3[3] = 0;
      pa[qj][3] = p3;
    }

    // O = P @ V via 16x16x16 (vT is wave-private; lgkm ordering compiler-handled)
    f32x4 acc2[4][2] = {};
#pragma unroll
    for (int dt = 0; dt < 2; dt++) {
      bf16x4 vb[4];
#pragma unroll
      for (int ki = 0; ki < 4; ki++)
        vb[ki] = *reinterpret_cast<const bf16x4*>(&vT[dt * 16 + lr][ki * 16 + lg * 4]);
      __builtin_amdgcn_s_setprio(1);
#pragma unroll
      for (int qj = 0; qj < 4; qj++)
#pragma unroll
        for (int ki = 0; ki < 4; ki++)
          acc2[qj][dt] = mfma16(pa[qj][ki], vb[ki], acc2[qj][dt]);
      __builtin_amdgcn_s_setprio(0);
    }

    // store attn_out (bf16); P was pre-normalized
#pragma unroll
    for (int qj = 0; qj < 4; qj++)
#pragma unroll
      for (int r = 0; r < 4; r++) {
        int row = qj * 16 + lg * 4 + r;
        if (row < 49) {
#pragma unroll
          for (int dt = 0; dt < 2; dt++) {
            int col = h * 32 + dt * 16 + lr;
            attn_out[((size_t)b * 49 + row) * 384 + col] = __float2bfloat16(acc2[qj][dt][r]);
          }
        }
      }
  }
}

// ---------------------------------------------------------------------------
// launch
// ---------------------------------------------------------------------------
extern "C" void kernel_launch(void* const* d_in, const int* in_sizes, int n_in,
                              void* d_out, int out_size, void* d_ws, size_t ws_size,
                              hipStream_t stream) {
  const float* x      = (const float*)d_in[0];
  const float* mask   = (const float*)d_in[1];
  const int*   posidx = (const int*)d_in[2];
  const float* table  = (const float*)d_in[3];
  const float* w_qkv  = (const float*)d_in[4];
  const float* b_qkv  = (const float*)d_in[5];
  const float* w_proj = (const float*)d_in[6];
  const float* b_proj = (const float*)d_in[7];
  float* out = (float*)d_out;

  char* ws = (char*)d_ws;
  bf16*  wqkvb  = (bf16*)(ws + 0);            // 1152*384    bf16 =    884,736 B
  bf16*  wprojb = (bf16*)(ws + 884736);       // 384*384     bf16 =    294,912 B
  bf16*  qkv    = (bf16*)(ws + 1179648);      // 50176*1152  bf16 = 115,605,504 B
  bf16*  aout   = (bf16*)(ws + 116785152);    // 50176*384   bf16 = 38,535,168 B
  bf16*  addend = (bf16*)(ws + 155320320);    // 64*12*49*64 bf16 =  4,816,896 B

  // prep: weight cvt + addend table (x is consumed as f32 by the GEMM)
  prep_kernel<<<9984, 256, 0, stream>>>(w_qkv, wqkvb, w_proj, wprojb,
                                        mask, posidx, table, addend);

  // qkv = x @ w_qkv^T + b_qkv   (M=50176, N=1152, K=384); A = f32 x direct
  gemm_qkv<<<392 * 9, 256, 0, stream>>>(x, wqkvb, b_qkv, qkv,
                                        50176, 1152, 384, 9, 392 * 9);

  // attention: 2 heads per wave, 4 waves per block
  attn_kernel<<<1536, 256, 0, stream>>>(qkv, addend, aout);

  // out = attn_out @ w_proj^T + b_proj   (M=50176, N=384, K=384)
  gemm_bt<<<392 * 3, 256, 0, stream>>>(aout, wprojb, b_proj, out,
                                       50176, 384, 384, 3, 392 * 3);
}

// Round 19
// 171.089 us; speedup vs baseline: 1.2533x; 1.2533x over previous
//
#include <hip/hip_runtime.h>
#include <hip/hip_bf16.h>

typedef __hip_bfloat16 bf16;
typedef __attribute__((ext_vector_type(4))) float f32x4;
typedef __attribute__((ext_vector_type(8))) short bf16x8;  // 8 bf16 in 4 VGPRs
typedef __attribute__((ext_vector_type(4))) short bf16x4;  // 4 bf16 in 2 VGPRs

// ---------------------------------------------------------------------------
// helpers
// ---------------------------------------------------------------------------
__device__ __forceinline__ void gload_lds16(const bf16* g, bf16* l) {
  __builtin_amdgcn_global_load_lds(
      (const __attribute__((address_space(1))) unsigned int*)(const void*)g,
      (__attribute__((address_space(3))) unsigned int*)(void*)l,
      16, 0, 0);
}

// XCD-contiguous bijective swizzle; REQUIRES nwg % 8 == 0.
__device__ __forceinline__ int xcd_swz(int orig, int nwg) {
  return (orig & 7) * (nwg >> 3) + (orig >> 3);
}

__device__ __forceinline__ float b2f(ushort u) {
  return __uint_as_float(((unsigned)u) << 16);
}

// 16x16x16 bf16 MFMA (K=16): A-frag = lane{row=l&15, k=(l>>4)*4+0..3}
#if defined(__has_builtin)
#if __has_builtin(__builtin_amdgcn_mfma_f32_16x16x16bf16_1k)
#define HAVE_MFMA16_BUILTIN 1
#endif
#endif
__device__ __forceinline__ f32x4 mfma16(bf16x4 a, bf16x4 b, f32x4 c) {
#ifdef HAVE_MFMA16_BUILTIN
  return __builtin_amdgcn_mfma_f32_16x16x16bf16_1k(a, b, c, 0, 0, 0);
#else
  asm("v_mfma_f32_16x16x16_bf16 %0, %1, %2, %0" : "+v"(c) : "v"(a), "v"(b));
  return c;
#endif
}

// ---------------------------------------------------------------------------
// merged prep: x->bf16 (blocks [0,18816)), weights->bf16 ([18816,19392)),
// addend table ([19392,28800)). One launch instead of three.
// ---------------------------------------------------------------------------
__global__ void prep_kernel(
    const float* __restrict__ x, bf16* __restrict__ xb,
    const float* __restrict__ wq, bf16* __restrict__ wqb,
    const float* __restrict__ wp, bf16* __restrict__ wpb,
    const float* __restrict__ mask, const int* __restrict__ pos,
    const float* __restrict__ table, bf16* __restrict__ addend) {
  const int bid = blockIdx.x;
  if (bid < 18816) {                       // x: 19,267,584 f32 -> bf16
    size_t i = ((size_t)bid * 256 + threadIdx.x) * 4;
    float4 v = *reinterpret_cast<const float4*>(x + i);
    bf16 o[4] = {__float2bfloat16(v.x), __float2bfloat16(v.y),
                 __float2bfloat16(v.z), __float2bfloat16(v.w)};
    *reinterpret_cast<ushort4*>(xb + i) = *reinterpret_cast<const ushort4*>(o);
  } else if (bid < 19392) {                // w_qkv (442368) + w_proj (147456)
    int t = (bid - 18816) * 256 + threadIdx.x;
    const float* src;
    bf16* dst;
    size_t i;
    if (t < 110592) {
      src = wq; dst = wqb; i = (size_t)t * 4;
    } else {
      src = wp; dst = wpb; i = (size_t)(t - 110592) * 4;
    }
    float4 v = *reinterpret_cast<const float4*>(src + i);
    bf16 o[4] = {__float2bfloat16(v.x), __float2bfloat16(v.y),
                 __float2bfloat16(v.z), __float2bfloat16(v.w)};
    *reinterpret_cast<ushort4*>(dst + i) = *reinterpret_cast<const ushort4*>(o);
  } else {                                 // addend: 2,408,448 elems
    int idx = (bid - 19392) * 256 + threadIdx.x;
    int c   = idx & 63;
    int rh  = idx >> 6;
    int row = rh % 49;
    int h   = (rh / 49) % 12;
    int w   = rh / (49 * 12);
    int k   = ((c >> 2) & 3) * 16 + (c >> 4) * 4 + (c & 3);
    float v = -1e30f;
    if (k < 49) {
      float m = mask[(w * 49 + row) * 49 + k];
      if (m != 0.0f) {
        v = m;
      } else {
        bool is64 = (pos[1] == 0) & (pos[3] == 0) & (pos[5] == 0) & (pos[7] == 0) &
                    (pos[9] == 0) & (pos[11] == 0) & (pos[13] == 0) & (pos[15] == 0);
        int pi = (w * 49 + row) * 49 + k;
        int p = is64 ? pos[2 * pi] : pos[pi];
        v = table[p * 12 + h];
      }
    }
    addend[idx] = __float2bfloat16(v);
  }
}

// ---------------------------------------------------------------------------
// GEMM: C[M,N] = A[M,K] @ B[N,K]^T + bias[N]   (A,B bf16 row-major K-contig)
// 128x128 tile, BK=32, 4 waves (2x2 of 64x64), global_load_lds width 16.
// 3-buffer, 2-deep prefetch with COUNTED vmcnt (T4) + conflict-free XOR
// swizzle via pre-swizzled global source (R14: SQ_LDS_BANK_CONFLICT -> 0).
// Best measured structure across 9 structural probes.
// ---------------------------------------------------------------------------
template <bool OUT_BF16>
__global__ __launch_bounds__(256) void gemm_bt(
    const bf16* __restrict__ A, const bf16* __restrict__ Bm,
    const float* __restrict__ bias, void* __restrict__ Cout,
    int M, int N, int K, int nbn, int nwg) {
  __shared__ bf16 As[3 * 128 * 32];
  __shared__ bf16 Bs[3 * 128 * 32];
  const int t = threadIdx.x;
  const int lane = t & 63;
  const int w = t >> 6, wr = w >> 1, wc = w & 1;
  const int lid = xcd_swz(blockIdx.x, nwg);
  const int bm = lid / nbn, bn = lid % nbn;
  const int lr = lane & 15, lg = lane >> 4;

  const int sc = (t & 3) ^ ((t >> 3) & 3);
  const bf16* ag = A + ((size_t)(bm * 128 + (t >> 2))) * K + sc * 8;
  const bf16* bg = Bm + ((size_t)(bn * 128 + (t >> 2))) * K + sc * 8;
  const size_t rstep = (size_t)64 * K;
  const int loff = t * 8;

  auto stage = [&](int tt) {
    const int bi = tt % 3;
    bf16* ad = As + bi * 4096 + loff;
    bf16* bd = Bs + bi * 4096 + loff;
    const bf16* as_ = ag + tt * 32;
    const bf16* bs_ = bg + tt * 32;
    gload_lds16(as_, ad);
    gload_lds16(as_ + rstep, ad + 2048);
    gload_lds16(bs_, bd);
    gload_lds16(bs_ + rstep, bd + 2048);
  };

  f32x4 acc[4][4] = {};
  const int nt = K >> 5;

  stage(0);
  stage(1);

  const int lgs = lg ^ ((lr >> 1) & 3);

  for (int kt = 0; kt < nt; ++kt) {
    if (kt + 1 < nt)
      asm volatile("s_waitcnt vmcnt(4)" ::: "memory");
    else
      asm volatile("s_waitcnt vmcnt(0)" ::: "memory");
    __builtin_amdgcn_s_barrier();
    if (kt + 2 < nt) stage(kt + 2);

    const int bi = kt % 3;
    bf16x8 af[4], bff[4];
    const bf16* ab = As + bi * 4096 + (wr * 64 + lr) * 32 + lgs * 8;
    const bf16* bb = Bs + bi * 4096 + (wc * 64 + lr) * 32 + lgs * 8;
#pragma unroll
    for (int i = 0; i < 4; i++) af[i] = *reinterpret_cast<const bf16x8*>(ab + i * 16 * 32);
#pragma unroll
    for (int j = 0; j < 4; j++) bff[j] = *reinterpret_cast<const bf16x8*>(bb + j * 16 * 32);
#pragma unroll
    for (int i = 0; i < 4; i++)
#pragma unroll
      for (int j = 0; j < 4; j++)
        acc[i][j] = __builtin_amdgcn_mfma_f32_16x16x32_bf16(af[i], bff[j], acc[i][j], 0, 0, 0);
  }

#pragma unroll
  for (int i = 0; i < 4; i++) {
    int row0 = bm * 128 + wr * 64 + i * 16 + lg * 4;
#pragma unroll
    for (int j = 0; j < 4; j++) {
      int col = bn * 128 + wc * 64 + j * 16 + lr;
      float bv = bias[col];
#pragma unroll
      for (int r = 0; r < 4; r++) {
        float v = acc[i][j][r] + bv;
        if (OUT_BF16)
          ((bf16*)Cout)[(size_t)(row0 + r) * N + col] = __float2bfloat16(v);
        else
          ((float*)Cout)[(size_t)(row0 + r) * N + col] = v;
      }
    }
  }
}

// ---------------------------------------------------------------------------
// fused window attention: TWO heads per wave (ILP), 4 waves per block.
// S^T = mfma(K,Q) -> lane-local no-max softmax -> PV from registers (16x16x16).
// Both heads' Q/K loads + V staging issued up front (latency overlap).
// ---------------------------------------------------------------------------
__global__ __launch_bounds__(256) void attn_kernel(
    const bf16* __restrict__ qkv, const bf16* __restrict__ addend,
    bf16* __restrict__ attn_out) {
  const int bid = xcd_swz(blockIdx.x, 1536);
  const int wv = threadIdx.x >> 6;
  const int p = bid * 4 + wv;
  const int b = p / 6;
  const int h0 = (p % 6) * 2;          // handles h0, h0+1
  const int w = b & 63;
  const int lane = threadIdx.x & 63;
  const int lr = lane & 15, lg = lane >> 4;
  const float scale = 0.17677669529663687f;  // 32^-0.5

  __shared__ ushort vT_all[4][2][32][72];   // [wave][head][d][k], 36.9 KB

  const size_t base = (size_t)b * 49 * 1152;

  // --- issue BOTH heads' Q/K loads up front (rows >= 49 clamped to 48)
  bf16x8 qf[2][4], kf[2][4];
#pragma unroll
  for (int hh = 0; hh < 2; hh++) {
    const int h = h0 + hh;
#pragma unroll
    for (int i = 0; i < 4; i++) {
      int rw = i * 16 + lr;
      int row = rw < 49 ? rw : 48;
      qf[hh][i] = *reinterpret_cast<const bf16x8*>(
          qkv + base + (size_t)row * 1152 + h * 32 + lg * 8);
      kf[hh][i] = *reinterpret_cast<const bf16x8*>(
          qkv + base + (size_t)row * 1152 + 384 + h * 32 + lg * 8);
    }
  }

  // --- stage BOTH heads' V transposed: vT[d][k] = V[k][d]
#pragma unroll
  for (int hh = 0; hh < 2; hh++) {
    ushort(*vT)[72] = vT_all[wv][hh];
    const int h = h0 + hh;
    if (lane < 49) {
#pragma unroll
      for (int c4 = 0; c4 < 4; c4++) {
        bf16x8 vv = *reinterpret_cast<const bf16x8*>(
            qkv + base + (size_t)lane * 1152 + 768 + h * 32 + c4 * 8);
#pragma unroll
        for (int cc = 0; cc < 8; cc++) vT[c4 * 8 + cc][lane] = (ushort)vv[cc];
      }
    } else {
#pragma unroll
      for (int c = 0; c < 32; c++) vT[c][lane] = 0;
    }
  }

  // --- per head (serial to cap VGPR): QK^T, no-max softmax, PV, store
#pragma unroll
  for (int hh = 0; hh < 2; hh++) {
    const int h = h0 + hh;
    ushort(*vT)[72] = vT_all[wv][hh];
    const bf16* add_base = addend + (size_t)(w * 12 + h) * 49 * 64;
    bf16x4 pa[4][4];   // [qj][ki]
#pragma unroll
    for (int qj = 0; qj < 4; qj++) {
      f32x4 s[4] = {};
      __builtin_amdgcn_s_setprio(1);
#pragma unroll
      for (int ki = 0; ki < 4; ki++)
        s[ki] = __builtin_amdgcn_mfma_f32_16x16x32_bf16(kf[hh][ki], qf[hh][qj], s[ki], 0, 0, 0);
      __builtin_amdgcn_s_setprio(0);

      int q = qj * 16 + lr;
      int qc = q < 49 ? q : 48;
      const ushort* ap_ = (const ushort*)(add_base + (size_t)qc * 64 + lg * 16);
      bf16x8 a0 = *reinterpret_cast<const bf16x8*>(ap_);      // ki 0,1
      bf16x8 a1 = *reinterpret_cast<const bf16x8*>(ap_ + 8);  // ki 2,3
      float v[12];
      float sum = 0.f;
#pragma unroll
      for (int u = 0; u < 8; u++) {   // ki 0,1
        v[u] = __expf(s[u >> 2][u & 3] * scale + b2f((ushort)a0[u]));
        sum += v[u];
      }
#pragma unroll
      for (int u = 0; u < 4; u++) {   // ki 2
        v[8 + u] = __expf(s[2][u] * scale + b2f((ushort)a1[u]));
        sum += v[8 + u];
      }
      // ki 3: only k=48 is real (lg==0, r==0); its addend is a1[4]
      float e48 = (lg == 0) ? __expf(s[3][0] * scale + b2f((ushort)a1[4])) : 0.0f;
      sum += e48;
      sum += __shfl_xor(sum, 16, 64);
      sum += __shfl_xor(sum, 32, 64);
      float rs = 1.0f / sum;
#pragma unroll
      for (int ki = 0; ki < 3; ki++) {
        bf16x4 pk;
#pragma unroll
        for (int r = 0; r < 4; r++)
          pk[r] = (short)__bfloat16_as_ushort(__float2bfloat16(v[ki * 4 + r] * rs));
        pa[qj][ki] = pk;
      }
      bf16x4 p3;
      p3[0] = (short)__bfloat16_as_ushort(__float2bfloat16(e48 * rs));
      p3[1] = 0; p3[2] = 0; p3[3] = 0;
      pa[qj][3] = p3;
    }

    // O = P @ V via 16x16x16 (vT is wave-private; lgkm ordering compiler-handled)
    f32x4 acc2[4][2] = {};
#pragma unroll
    for (int dt = 0; dt < 2; dt++) {
      bf16x4 vb[4];
#pragma unroll
      for (int ki = 0; ki < 4; ki++)
        vb[ki] = *reinterpret_cast<const bf16x4*>(&vT[dt * 16 + lr][ki * 16 + lg * 4]);
      __builtin_amdgcn_s_setprio(1);
#pragma unroll
      for (int qj = 0; qj < 4; qj++)
#pragma unroll
        for (int ki = 0; ki < 4; ki++)
          acc2[qj][dt] = mfma16(pa[qj][ki], vb[ki], acc2[qj][dt]);
      __builtin_amdgcn_s_setprio(0);
    }

    // store attn_out (bf16); P was pre-normalized
#pragma unroll
    for (int qj = 0; qj < 4; qj++)
#pragma unroll
      for (int r = 0; r < 4; r++) {
        int row = qj * 16 + lg * 4 + r;
        if (row < 49) {
#pragma unroll
          for (int dt = 0; dt < 2; dt++) {
            int col = h * 32 + dt * 16 + lr;
            attn_out[((size_t)b * 49 + row) * 384 + col] = __float2bfloat16(acc2[qj][dt][r]);
          }
        }
      }
  }
}

// ---------------------------------------------------------------------------
// launch
// ---------------------------------------------------------------------------
extern "C" void kernel_launch(void* const* d_in, const int* in_sizes, int n_in,
                              void* d_out, int out_size, void* d_ws, size_t ws_size,
                              hipStream_t stream) {
  const float* x      = (const float*)d_in[0];
  const float* mask   = (const float*)d_in[1];
  const int*   posidx = (const int*)d_in[2];
  const float* table  = (const float*)d_in[3];
  const float* w_qkv  = (const float*)d_in[4];
  const float* b_qkv  = (const float*)d_in[5];
  const float* w_proj = (const float*)d_in[6];
  const float* b_proj = (const float*)d_in[7];
  float* out = (float*)d_out;

  char* ws = (char*)d_ws;
  bf16*  xb     = (bf16*)(ws + 0);            // 50176*384   bf16 = 38,535,168 B
  bf16*  wqkvb  = (bf16*)(ws + 38535168);     // 1152*384    bf16 =    884,736 B
  bf16*  wprojb = (bf16*)(ws + 39419904);     // 384*384     bf16 =    294,912 B
  bf16*  qkv    = (bf16*)(ws + 39714816);     // 50176*1152  bf16 = 115,605,504 B
  bf16*  aout   = (bf16*)(ws + 155320320);    // 50176*384   bf16 = 38,535,168 B
  bf16*  addend = (bf16*)(ws + 193855488);    // 64*12*49*64 bf16 =  4,816,896 B

  // merged prep: x cvt + weight cvt + addend table in one launch
  prep_kernel<<<28800, 256, 0, stream>>>(x, xb, w_qkv, wqkvb, w_proj, wprojb,
                                         mask, posidx, table, addend);

  // qkv = x @ w_qkv^T + b_qkv   (M=50176, N=1152, K=384)
  gemm_bt<true><<<392 * 9, 256, 0, stream>>>(xb, wqkvb, b_qkv, qkv,
                                             50176, 1152, 384, 9, 392 * 9);

  // attention: 2 heads per wave, 4 waves per block
  attn_kernel<<<1536, 256, 0, stream>>>(qkv, addend, aout);

  // out = attn_out @ w_proj^T + b_proj   (M=50176, N=384, K=384)
  gemm_bt<false><<<392 * 3, 256, 0, stream>>>(aout, wprojb, b_proj, out,
                                              50176, 384, 384, 3, 392 * 3);
}